// Round 5
// baseline (413.294 us; speedup 1.0000x reference)
//
#include <hip/hip_runtime.h>
#include <cmath>

#define NB 8
#define NS 32
#define NP 8
#define NV 8000
#define ND 128
#define CONC 5.0f
#define EPS 1e-8f

#define TROWS 8            // slots per k_B tile
#define USPLIT 25          // u-dimension splits: 8000 = 25*320
#define URANGE 320
#define UCHUNK 64
#define NCHUNK (URANGE / UCHUNK)   // 5
#define MAXSLOTS (NB * NS * NP)    // 2048

// ---- workspace layout (4-byte units) ----
#define WS_CNT    0        // int counter
#define WS_METAO  16       // int[2048]
#define WS_SCALE  2064     // float[2048]
#define WS_CN     4112     // float[1024]
#define WS_COS    5136     // float[64000]
#define WS_MEANJ  69136    // float[32768]
#define WS_P      101904   // float[2048*8000] = 65.5 MB

// ---------------------------------------------------------------------------
// k_mean: per (b,s), ragged mean over P.  grid=NB*NS, block=ND
// ---------------------------------------------------------------------------
__global__ void k_mean(const int* __restrict__ concepts,
                       const int* __restrict__ concepts_length,
                       const float* __restrict__ embed_w,
                       float* __restrict__ mean_j) {
    const int bs = blockIdx.x;
    const int d = threadIdx.x;
    const int len = concepts_length[bs];
    float sum = 0.0f;
    for (int p = 0; p < len; ++p) {
        const int c = concepts[bs * NP + p];
        sum += embed_w[(size_t)c * ND + d];
    }
    mean_j[(size_t)bs * ND + d] = sum / (float)(len > 0 ? len : 1);
}

// ---------------------------------------------------------------------------
// k_ctx2: per b, mean over valid segments + normalize.  grid=NB, block=ND
// ---------------------------------------------------------------------------
__global__ void k_ctx2(const int* __restrict__ seg_len,
                       const float* __restrict__ mean_j,
                       float* __restrict__ cn) {
    const int b = blockIdx.x;
    const int d = threadIdx.x;
    const int sl = seg_len[b];
    float acc = 0.0f;
    for (int s = 0; s < sl; ++s) acc += mean_j[(size_t)(b * NS + s) * ND + d];
    acc /= (float)sl;
    float ss = acc * acc;
    #pragma unroll
    for (int m = 1; m < 64; m <<= 1) ss += __shfl_xor(ss, m);
    __shared__ float sred[2];
    if ((d & 63) == 0) sred[d >> 6] = ss;
    __syncthreads();
    const float tot = sred[0] + sred[1];
    cn[b * ND + d] = acc / fmaxf(sqrtf(tot), EPS);
}

// ---------------------------------------------------------------------------
// k_cos: cos[b][v] = |cn[b] . normalize(kb[v])|.  grid=NV/8, block=256
// ---------------------------------------------------------------------------
__global__ __launch_bounds__(256) void k_cos(const float* __restrict__ kb,
                                             const float* __restrict__ cn,
                                             float* __restrict__ cos_bv) {
    __shared__ float s_cn[NB * ND];
    const int t = threadIdx.x;
    for (int i = t; i < NB * ND; i += 256) s_cn[i] = cn[i];
    __syncthreads();

    const int v = blockIdx.x * 8 + (t >> 5);
    const int l = t & 31;
    const float4 kv = *reinterpret_cast<const float4*>(kb + (size_t)v * ND + (l << 2));
    float ss = kv.x * kv.x + kv.y * kv.y + kv.z * kv.z + kv.w * kv.w;
    #pragma unroll
    for (int m = 1; m < 32; m <<= 1) ss += __shfl_xor(ss, m);
    const float inv = 1.0f / fmaxf(sqrtf(ss), EPS);
    #pragma unroll
    for (int b = 0; b < NB; ++b) {
        const float4 cv = *reinterpret_cast<const float4*>(&s_cn[b * ND + (l << 2)]);
        float dot = kv.x * cv.x + kv.y * cv.y + kv.z * cv.z + kv.w * cv.w;
        #pragma unroll
        for (int m = 1; m < 32; m <<= 1) dot += __shfl_xor(dot, m);
        if (l == 0) cos_bv[b * NV + v] = fabsf(dot * inv);
    }
}

// ---------------------------------------------------------------------------
// k_A: per valid triple: softmax stats, materialize p = exp(w-gmax) into
// pbuf[slot][8000], compact slot list.  grid=2048, block=256.
// ---------------------------------------------------------------------------
__global__ __launch_bounds__(256) void k_A(
        const int* __restrict__ concepts,
        const int* __restrict__ concepts_length,
        const int* __restrict__ seg_len,
        const float* __restrict__ edge,
        const float* __restrict__ aff,
        const float* __restrict__ lam,
        const float* __restrict__ cos_bv,
        int* __restrict__ counter,
        int* __restrict__ meta_out,
        float* __restrict__ f_scale,
        float* __restrict__ pbuf) {
    const int idx = blockIdx.x;
    const int b = idx >> 8;
    const int s = (idx >> 3) & 31;
    const int p = idx & 7;
    if (s >= seg_len[b]) return;
    const int len = concepts_length[b * NS + s];
    if (p >= len) return;
    const int c = concepts[idx];

    const int t = threadIdx.x;
    const float* __restrict__ erow = edge + (size_t)c * NV;
    float4 ev[8];
    float lmax = -INFINITY, lmin = INFINITY;
    #pragma unroll
    for (int k = 0; k < 8; ++k) {
        const int f = t + (k << 8);            // float4 index, valid < 2000
        if (f < 2000) {
            const float4 e = *reinterpret_cast<const float4*>(erow + (f << 2));
            ev[k] = e;
            lmax = fmaxf(lmax, fmaxf(fmaxf(e.x, e.y), fmaxf(e.z, e.w)));
            lmin = fminf(lmin, fminf(fminf(e.x, e.y), fminf(e.z, e.w)));
        }
    }
    #pragma unroll
    for (int m = 1; m < 64; m <<= 1) {
        lmax = fmaxf(lmax, __shfl_xor(lmax, m));
        lmin = fminf(lmin, __shfl_xor(lmin, m));
    }
    __shared__ float s_mn[4], s_mx[4], s_wm[4], s_sum[4];
    __shared__ int s_slot;
    if (t == 0) s_slot = atomicAdd(counter, 1);
    if ((t & 63) == 0) { s_mn[t >> 6] = lmin; s_mx[t >> 6] = lmax; }
    __syncthreads();
    const float rmin = fminf(fminf(s_mn[0], s_mn[1]), fminf(s_mn[2], s_mn[3]));
    const float rmax = fmaxf(fmaxf(s_mx[0], s_mx[1]), fmaxf(s_mx[2], s_mx[3]));
    const int slot = s_slot;
    const float rng = rmax - rmin;
    const float inv_rng = 1.0f / (rng + (rng == 0.0f ? 1.0f : 0.0f));

    const float* __restrict__ cosb = cos_bv + b * NV;
    float wmax = -INFINITY;
    #pragma unroll
    for (int k = 0; k < 8; ++k) {
        const int f = t + (k << 8);
        if (f < 2000) {
            const int u = f << 2;
            const float4 l4 = *reinterpret_cast<const float4*>(lam + u);
            const float4 a4 = *reinterpret_cast<const float4*>(aff + u);
            const float4 c4 = *reinterpret_cast<const float4*>(cosb + u);
            float4 e = ev[k];
            e.x *= inv_rng; e.y *= inv_rng; e.z *= inv_rng; e.w *= inv_rng;
            float4 w;
            w.x = (l4.x * e.x * c4.x + (1.0f - l4.x) * ((e.x > 0.0f) ? 1.0f : 0.0f) * a4.x) * CONC;
            w.y = (l4.y * e.y * c4.y + (1.0f - l4.y) * ((e.y > 0.0f) ? 1.0f : 0.0f) * a4.y) * CONC;
            w.z = (l4.z * e.z * c4.z + (1.0f - l4.z) * ((e.z > 0.0f) ? 1.0f : 0.0f) * a4.z) * CONC;
            w.w = (l4.w * e.w * c4.w + (1.0f - l4.w) * ((e.w > 0.0f) ? 1.0f : 0.0f) * a4.w) * CONC;
            ev[k] = w;
            wmax = fmaxf(wmax, fmaxf(fmaxf(w.x, w.y), fmaxf(w.z, w.w)));
        }
    }
    #pragma unroll
    for (int m = 1; m < 64; m <<= 1) wmax = fmaxf(wmax, __shfl_xor(wmax, m));
    if ((t & 63) == 0) s_wm[t >> 6] = wmax;
    __syncthreads();
    const float gmax = fmaxf(fmaxf(s_wm[0], s_wm[1]), fmaxf(s_wm[2], s_wm[3]));

    float* __restrict__ prow = pbuf + (size_t)slot * NV;
    float lsum = 0.0f;
    #pragma unroll
    for (int k = 0; k < 8; ++k) {
        const int f = t + (k << 8);
        if (f < 2000) {
            float4 pe;
            pe.x = __expf(ev[k].x - gmax);
            pe.y = __expf(ev[k].y - gmax);
            pe.z = __expf(ev[k].z - gmax);
            pe.w = __expf(ev[k].w - gmax);
            *reinterpret_cast<float4*>(prow + (f << 2)) = pe;
            lsum += pe.x + pe.y + pe.z + pe.w;
        }
    }
    #pragma unroll
    for (int m = 1; m < 64; m <<= 1) lsum += __shfl_xor(lsum, m);
    if ((t & 63) == 0) s_sum[t >> 6] = lsum;
    __syncthreads();
    if (t == 0) {
        const float total = s_sum[0] + s_sum[1] + s_sum[2] + s_sum[3];
        meta_out[slot] = b * NS + s;
        f_scale[slot] = 1.0f / (total * (float)len);
    }
}

// ---------------------------------------------------------------------------
// k_B: batched GEMV with register-level kb reuse; p read from pbuf.
// grid=(MAXSLOTS/TROWS, USPLIT), block=256.
// ---------------------------------------------------------------------------
__global__ __launch_bounds__(256) void k_B(
        const float* __restrict__ kb,
        const int* __restrict__ counter,
        const int* __restrict__ meta_out,
        const float* __restrict__ f_scale,
        const float* __restrict__ pbuf,
        float* __restrict__ out) {
    const int count = counter[0];
    const int tile = blockIdx.x;
    if (tile * TROWS >= count) return;

    const int t = threadIdx.x;
    const int ug = t & 7;
    const int l = t >> 3;

    __shared__ int s_o[TROWS];
    __shared__ float s_sc[TROWS];
    __shared__ __align__(16) float s_p[UCHUNK * TROWS];  // [uu][slot], 2 KB

    if (t < TROWS) {
        const int slot = tile * TROWS + t;
        s_o[t]  = (slot < count) ? meta_out[slot] : 0;
        s_sc[t] = (slot < count) ? f_scale[slot] : 0.0f;
    }
    __syncthreads();

    const int u0 = blockIdx.y * URANGE;

    float4 acc[TROWS];
    #pragma unroll
    for (int j = 0; j < TROWS; ++j) acc[j] = make_float4(0.f, 0.f, 0.f, 0.f);

    for (int ch = 0; ch < NCHUNK; ++ch) {
        const int uc = u0 + ch * UCHUNK;

        // ---- stage p[uu][slot] from pbuf: 16 consecutive threads per row ----
        if (t < 128) {
            const int slot = t >> 4;          // 0..7
            const int q = t & 15;             // 0..15, float4 within 64 u
            const int row = tile * TROWS + slot;
            float4 pv = make_float4(0.f, 0.f, 0.f, 0.f);
            if (row < count)
                pv = *reinterpret_cast<const float4*>(pbuf + (size_t)row * NV + uc + (q << 2));
            const int uu = q << 2;
            s_p[(uu + 0) * TROWS + slot] = pv.x;
            s_p[(uu + 1) * TROWS + slot] = pv.y;
            s_p[(uu + 2) * TROWS + slot] = pv.z;
            s_p[(uu + 3) * TROWS + slot] = pv.w;
        }
        __syncthreads();

        // ---- compute: 8 u per thread, kb loaded once, used by 8 slots ----
        #pragma unroll
        for (int r = 0; r < 8; ++r) {
            const int uu = ug + (r << 3);
            const float4 kv = *reinterpret_cast<const float4*>(
                kb + (size_t)(uc + uu) * ND + (l << 2));
            const float4 p0 = *reinterpret_cast<const float4*>(&s_p[uu * TROWS]);
            const float4 p1 = *reinterpret_cast<const float4*>(&s_p[uu * TROWS + 4]);
            acc[0].x = fmaf(p0.x, kv.x, acc[0].x); acc[0].y = fmaf(p0.x, kv.y, acc[0].y);
            acc[0].z = fmaf(p0.x, kv.z, acc[0].z); acc[0].w = fmaf(p0.x, kv.w, acc[0].w);
            acc[1].x = fmaf(p0.y, kv.x, acc[1].x); acc[1].y = fmaf(p0.y, kv.y, acc[1].y);
            acc[1].z = fmaf(p0.y, kv.z, acc[1].z); acc[1].w = fmaf(p0.y, kv.w, acc[1].w);
            acc[2].x = fmaf(p0.z, kv.x, acc[2].x); acc[2].y = fmaf(p0.z, kv.y, acc[2].y);
            acc[2].z = fmaf(p0.z, kv.z, acc[2].z); acc[2].w = fmaf(p0.z, kv.w, acc[2].w);
            acc[3].x = fmaf(p0.w, kv.x, acc[3].x); acc[3].y = fmaf(p0.w, kv.y, acc[3].y);
            acc[3].z = fmaf(p0.w, kv.z, acc[3].z); acc[3].w = fmaf(p0.w, kv.w, acc[3].w);
            acc[4].x = fmaf(p1.x, kv.x, acc[4].x); acc[4].y = fmaf(p1.x, kv.y, acc[4].y);
            acc[4].z = fmaf(p1.x, kv.z, acc[4].z); acc[4].w = fmaf(p1.x, kv.w, acc[4].w);
            acc[5].x = fmaf(p1.y, kv.x, acc[5].x); acc[5].y = fmaf(p1.y, kv.y, acc[5].y);
            acc[5].z = fmaf(p1.y, kv.z, acc[5].z); acc[5].w = fmaf(p1.y, kv.w, acc[5].w);
            acc[6].x = fmaf(p1.z, kv.x, acc[6].x); acc[6].y = fmaf(p1.z, kv.y, acc[6].y);
            acc[6].z = fmaf(p1.z, kv.z, acc[6].z); acc[6].w = fmaf(p1.z, kv.w, acc[6].w);
            acc[7].x = fmaf(p1.w, kv.x, acc[7].x); acc[7].y = fmaf(p1.w, kv.y, acc[7].y);
            acc[7].z = fmaf(p1.w, kv.z, acc[7].z); acc[7].w = fmaf(p1.w, kv.w, acc[7].w);
        }
        __syncthreads();
    }

    // ---- butterfly reduce over ug (lane bits 0-2), lane ug keeps slot=ug ----
    float4 res = make_float4(0.f, 0.f, 0.f, 0.f);
    #pragma unroll
    for (int j = 0; j < TROWS; ++j) {
        float4 a = acc[j];
        #pragma unroll
        for (int m = 1; m <= 4; m <<= 1) {
            a.x += __shfl_xor(a.x, m);
            a.y += __shfl_xor(a.y, m);
            a.z += __shfl_xor(a.z, m);
            a.w += __shfl_xor(a.w, m);
        }
        if (ug == j) res = a;
    }

    const int myslot = tile * TROWS + ug;
    if (myslot < count) {
        const float sc = s_sc[ug];
        float* o = out + (size_t)s_o[ug] * ND + (l << 2);
        atomicAdd(o + 0, res.x * sc);
        atomicAdd(o + 1, res.y * sc);
        atomicAdd(o + 2, res.z * sc);
        atomicAdd(o + 3, res.w * sc);
    }
}

extern "C" void kernel_launch(void* const* d_in, const int* in_sizes, int n_in,
                              void* d_out, int out_size, void* d_ws, size_t ws_size,
                              hipStream_t stream) {
    const int*   concepts        = (const int*)d_in[0];
    const int*   concepts_length = (const int*)d_in[1];
    const int*   seg_len         = (const int*)d_in[2];
    const float* embed_w         = (const float*)d_in[3];
    const float* embed_kb_w      = (const float*)d_in[4];
    const float* edge_matrix     = (const float*)d_in[5];
    const float* affectiveness   = (const float*)d_in[6];
    const float* lam             = (const float*)d_in[7];
    float* out = (float*)d_out;

    float* wsf = (float*)d_ws;
    int*   wsi = (int*)d_ws;
    int*   counter  = wsi + WS_CNT;
    int*   meta_out = wsi + WS_METAO;
    float* f_scale  = wsf + WS_SCALE;
    float* cn       = wsf + WS_CN;
    float* cos_bv   = wsf + WS_COS;
    float* mean_j   = wsf + WS_MEANJ;
    float* pbuf     = wsf + WS_P;

    hipMemsetAsync(out, 0, (size_t)out_size * sizeof(float), stream);
    hipMemsetAsync(counter, 0, 64, stream);

    k_mean<<<NB * NS, ND, 0, stream>>>(concepts, concepts_length, embed_w, mean_j);
    k_ctx2<<<NB, ND, 0, stream>>>(seg_len, mean_j, cn);
    k_cos<<<NV / 8, 256, 0, stream>>>(embed_kb_w, cn, cos_bv);
    k_A<<<MAXSLOTS, 256, 0, stream>>>(concepts, concepts_length, seg_len,
                                      edge_matrix, affectiveness, lam, cos_bv,
                                      counter, meta_out, f_scale, pbuf);
    dim3 gB(MAXSLOTS / TROWS, USPLIT, 1);
    k_B<<<gB, 256, 0, stream>>>(embed_kb_w, counter, meta_out, f_scale, pbuf, out);
}

// Round 6
// 410.494 us; speedup vs baseline: 1.0068x; 1.0068x over previous
//
#include <hip/hip_runtime.h>
#include <cmath>

#define NB 8
#define NS 32
#define NP 8
#define NV 8000
#define ND 128
#define CONC 5.0f
#define EPS 1e-8f

#define TROWS 16           // slots per k_B tile
#define USPLIT 25          // u-dimension splits: 8000 = 25*320
#define URANGE 320
#define UCHUNK 64
#define NCHUNK (URANGE / UCHUNK)   // 5
#define ST 20              // padded LDS stride (floats) -> conflict-free b128
#define MAXSLOTS (NB * NS * NP)    // 2048

// ---- workspace layout (4-byte units) ----
#define WS_CNT    0        // int counter
#define WS_METAO  16       // int[2048]
#define WS_SCALE  2064     // float[2048]
#define WS_CN     4112     // float[1024]
#define WS_COS    5136     // float[64000]
#define WS_MEANJ  69136    // float[32768]
#define WS_P      101904   // float[2048*8000] = 65.5 MB

// ---------------------------------------------------------------------------
// k_mean: per (b,s) ragged mean over P; also zeroes out[] and counter.
// grid=NB*NS (256), block=ND (128): out has exactly 256*128 elements.
// ---------------------------------------------------------------------------
__global__ void k_mean(const int* __restrict__ concepts,
                       const int* __restrict__ concepts_length,
                       const float* __restrict__ embed_w,
                       float* __restrict__ mean_j,
                       float* __restrict__ out,
                       int* __restrict__ counter) {
    const int bs = blockIdx.x;
    const int d = threadIdx.x;
    out[bs * ND + d] = 0.0f;
    if (bs == 0 && d == 0) counter[0] = 0;
    const int len = concepts_length[bs];
    float sum = 0.0f;
    for (int p = 0; p < len; ++p) {
        const int c = concepts[bs * NP + p];
        sum += embed_w[(size_t)c * ND + d];
    }
    mean_j[(size_t)bs * ND + d] = sum / (float)(len > 0 ? len : 1);
}

// ---------------------------------------------------------------------------
// k_ctx2: per b, mean over valid segments + normalize.  grid=NB, block=ND
// ---------------------------------------------------------------------------
__global__ void k_ctx2(const int* __restrict__ seg_len,
                       const float* __restrict__ mean_j,
                       float* __restrict__ cn) {
    const int b = blockIdx.x;
    const int d = threadIdx.x;
    const int sl = seg_len[b];
    float acc = 0.0f;
    for (int s = 0; s < sl; ++s) acc += mean_j[(size_t)(b * NS + s) * ND + d];
    acc /= (float)sl;
    float ss = acc * acc;
    #pragma unroll
    for (int m = 1; m < 64; m <<= 1) ss += __shfl_xor(ss, m);
    __shared__ float sred[2];
    if ((d & 63) == 0) sred[d >> 6] = ss;
    __syncthreads();
    const float tot = sred[0] + sred[1];
    cn[b * ND + d] = acc / fmaxf(sqrtf(tot), EPS);
}

// ---------------------------------------------------------------------------
// k_cos: cos[b][v] = |cn[b] . normalize(kb[v])|.  grid=NV/8, block=256
// ---------------------------------------------------------------------------
__global__ __launch_bounds__(256) void k_cos(const float* __restrict__ kb,
                                             const float* __restrict__ cn,
                                             float* __restrict__ cos_bv) {
    __shared__ float s_cn[NB * ND];
    const int t = threadIdx.x;
    for (int i = t; i < NB * ND; i += 256) s_cn[i] = cn[i];
    __syncthreads();

    const int v = blockIdx.x * 8 + (t >> 5);
    const int l = t & 31;
    const float4 kv = *reinterpret_cast<const float4*>(kb + (size_t)v * ND + (l << 2));
    float ss = kv.x * kv.x + kv.y * kv.y + kv.z * kv.z + kv.w * kv.w;
    #pragma unroll
    for (int m = 1; m < 32; m <<= 1) ss += __shfl_xor(ss, m);
    const float inv = 1.0f / fmaxf(sqrtf(ss), EPS);
    #pragma unroll
    for (int b = 0; b < NB; ++b) {
        const float4 cv = *reinterpret_cast<const float4*>(&s_cn[b * ND + (l << 2)]);
        float dot = kv.x * cv.x + kv.y * cv.y + kv.z * cv.z + kv.w * cv.w;
        #pragma unroll
        for (int m = 1; m < 32; m <<= 1) dot += __shfl_xor(dot, m);
        if (l == 0) cos_bv[b * NV + v] = fabsf(dot * inv);
    }
}

// ---------------------------------------------------------------------------
// k_A: per valid triple: row min/max, then ONE fused pass computing
// p = exp(w) (no max subtraction -- w in [0, ~5], e^w <= ~150, f32-safe;
// the constant factor cancels in the softmax normalization), storing p to
// pbuf[slot][NV] and accumulating the sum.  grid=2048, block=256.
// ---------------------------------------------------------------------------
__global__ __launch_bounds__(256) void k_A(
        const int* __restrict__ concepts,
        const int* __restrict__ concepts_length,
        const int* __restrict__ seg_len,
        const float* __restrict__ edge,
        const float* __restrict__ aff,
        const float* __restrict__ lam,
        const float* __restrict__ cos_bv,
        int* __restrict__ counter,
        int* __restrict__ meta_out,
        float* __restrict__ f_scale,
        float* __restrict__ pbuf) {
    const int idx = blockIdx.x;
    const int b = idx >> 8;
    const int s = (idx >> 3) & 31;
    const int p = idx & 7;
    if (s >= seg_len[b]) return;
    const int len = concepts_length[b * NS + s];
    if (p >= len) return;
    const int c = concepts[idx];

    const int t = threadIdx.x;
    const float* __restrict__ erow = edge + (size_t)c * NV;
    float4 ev[8];
    float lmax = -INFINITY, lmin = INFINITY;
    #pragma unroll
    for (int k = 0; k < 8; ++k) {
        const int f = t + (k << 8);            // float4 index, valid < 2000
        if (f < 2000) {
            const float4 e = *reinterpret_cast<const float4*>(erow + (f << 2));
            ev[k] = e;
            lmax = fmaxf(lmax, fmaxf(fmaxf(e.x, e.y), fmaxf(e.z, e.w)));
            lmin = fminf(lmin, fminf(fminf(e.x, e.y), fminf(e.z, e.w)));
        }
    }
    #pragma unroll
    for (int m = 1; m < 64; m <<= 1) {
        lmax = fmaxf(lmax, __shfl_xor(lmax, m));
        lmin = fminf(lmin, __shfl_xor(lmin, m));
    }
    __shared__ float s_mn[4], s_mx[4], s_sum[4];
    __shared__ int s_slot;
    if (t == 0) s_slot = atomicAdd(counter, 1);
    if ((t & 63) == 0) { s_mn[t >> 6] = lmin; s_mx[t >> 6] = lmax; }
    __syncthreads();
    const float rmin = fminf(fminf(s_mn[0], s_mn[1]), fminf(s_mn[2], s_mn[3]));
    const float rmax = fmaxf(fmaxf(s_mx[0], s_mx[1]), fmaxf(s_mx[2], s_mx[3]));
    const int slot = s_slot;
    const float rng = rmax - rmin;
    const float inv_rng = 1.0f / (rng + (rng == 0.0f ? 1.0f : 0.0f));

    // fused: w -> exp -> store -> sum
    const float* __restrict__ cosb = cos_bv + b * NV;
    float* __restrict__ prow = pbuf + (size_t)slot * NV;
    float lsum = 0.0f;
    #pragma unroll
    for (int k = 0; k < 8; ++k) {
        const int f = t + (k << 8);
        if (f < 2000) {
            const int u = f << 2;
            const float4 l4 = *reinterpret_cast<const float4*>(lam + u);
            const float4 a4 = *reinterpret_cast<const float4*>(aff + u);
            const float4 c4 = *reinterpret_cast<const float4*>(cosb + u);
            float4 e = ev[k];
            e.x *= inv_rng; e.y *= inv_rng; e.z *= inv_rng; e.w *= inv_rng;
            float4 pe;
            pe.x = __expf((l4.x * e.x * c4.x + (1.0f - l4.x) * ((e.x > 0.0f) ? 1.0f : 0.0f) * a4.x) * CONC);
            pe.y = __expf((l4.y * e.y * c4.y + (1.0f - l4.y) * ((e.y > 0.0f) ? 1.0f : 0.0f) * a4.y) * CONC);
            pe.z = __expf((l4.z * e.z * c4.z + (1.0f - l4.z) * ((e.z > 0.0f) ? 1.0f : 0.0f) * a4.z) * CONC);
            pe.w = __expf((l4.w * e.w * c4.w + (1.0f - l4.w) * ((e.w > 0.0f) ? 1.0f : 0.0f) * a4.w) * CONC);
            *reinterpret_cast<float4*>(prow + (f << 2)) = pe;
            lsum += pe.x + pe.y + pe.z + pe.w;
        }
    }
    #pragma unroll
    for (int m = 1; m < 64; m <<= 1) lsum += __shfl_xor(lsum, m);
    if ((t & 63) == 0) s_sum[t >> 6] = lsum;
    __syncthreads();
    if (t == 0) {
        const float total = s_sum[0] + s_sum[1] + s_sum[2] + s_sum[3];
        meta_out[slot] = b * NS + s;
        f_scale[slot] = 1.0f / (total * (float)len);
    }
}

// ---------------------------------------------------------------------------
// k_B: batched GEMV, 16 slots share each kb float4 (register reuse);
// p staged via LDS (stride-20 padded, conflict-free b128 reads) with
// register prefetch of the next chunk.  grid=(128, 25), block=256.
// ---------------------------------------------------------------------------
__global__ __launch_bounds__(256) void k_B(
        const float* __restrict__ kb,
        const int* __restrict__ counter,
        const int* __restrict__ meta_out,
        const float* __restrict__ f_scale,
        const float* __restrict__ pbuf,
        float* __restrict__ out) {
    const int count = counter[0];
    const int tile = blockIdx.x;
    if (tile * TROWS >= count) return;

    const int t = threadIdx.x;
    const int ug = t & 7;          // u-group, lane bits 0-2
    const int l = t >> 3;          // d-group 0..31

    __shared__ int s_o[TROWS];
    __shared__ float s_sc[TROWS];
    __shared__ __align__(16) float s_p[UCHUNK * ST];   // 5 KB

    if (t < TROWS) {
        const int slot = tile * TROWS + t;
        s_o[t]  = (slot < count) ? meta_out[slot] : 0;
        s_sc[t] = (slot < count) ? f_scale[slot] : 0.0f;
    }

    const int u0 = blockIdx.y * URANGE;
    const int srow = t >> 4;       // 0..15 slot for staging
    const int sq = t & 15;         // 0..15 float4 within 64 u
    const int prow_ok = (tile * TROWS + srow) < count;
    const float* __restrict__ pr = pbuf + (size_t)(tile * TROWS + srow) * NV;

    float4 acc[TROWS];
    #pragma unroll
    for (int j = 0; j < TROWS; ++j) acc[j] = make_float4(0.f, 0.f, 0.f, 0.f);

    // prefetch chunk 0
    float4 pv = make_float4(0.f, 0.f, 0.f, 0.f);
    if (prow_ok) pv = *reinterpret_cast<const float4*>(pr + u0 + (sq << 2));

    for (int ch = 0; ch < NCHUNK; ++ch) {
        // stage pv (chunk ch): p[uu][slot] at stride ST
        const int uu0 = sq << 2;
        s_p[(uu0 + 0) * ST + srow] = pv.x;
        s_p[(uu0 + 1) * ST + srow] = pv.y;
        s_p[(uu0 + 2) * ST + srow] = pv.z;
        s_p[(uu0 + 3) * ST + srow] = pv.w;
        // prefetch chunk ch+1
        float4 pnext = make_float4(0.f, 0.f, 0.f, 0.f);
        if (ch + 1 < NCHUNK && prow_ok)
            pnext = *reinterpret_cast<const float4*>(pr + u0 + (ch + 1) * UCHUNK + (sq << 2));
        __syncthreads();

        const int uc = u0 + ch * UCHUNK;
        #pragma unroll
        for (int r = 0; r < 8; ++r) {
            const int uu = ug + (r << 3);
            const float4 kv = *reinterpret_cast<const float4*>(
                kb + (size_t)(uc + uu) * ND + (l << 2));
            const float4 p0 = *reinterpret_cast<const float4*>(&s_p[uu * ST]);
            const float4 p1 = *reinterpret_cast<const float4*>(&s_p[uu * ST + 4]);
            const float4 p2 = *reinterpret_cast<const float4*>(&s_p[uu * ST + 8]);
            const float4 p3 = *reinterpret_cast<const float4*>(&s_p[uu * ST + 12]);
            acc[ 0].x = fmaf(p0.x, kv.x, acc[ 0].x); acc[ 0].y = fmaf(p0.x, kv.y, acc[ 0].y);
            acc[ 0].z = fmaf(p0.x, kv.z, acc[ 0].z); acc[ 0].w = fmaf(p0.x, kv.w, acc[ 0].w);
            acc[ 1].x = fmaf(p0.y, kv.x, acc[ 1].x); acc[ 1].y = fmaf(p0.y, kv.y, acc[ 1].y);
            acc[ 1].z = fmaf(p0.y, kv.z, acc[ 1].z); acc[ 1].w = fmaf(p0.y, kv.w, acc[ 1].w);
            acc[ 2].x = fmaf(p0.z, kv.x, acc[ 2].x); acc[ 2].y = fmaf(p0.z, kv.y, acc[ 2].y);
            acc[ 2].z = fmaf(p0.z, kv.z, acc[ 2].z); acc[ 2].w = fmaf(p0.z, kv.w, acc[ 2].w);
            acc[ 3].x = fmaf(p0.w, kv.x, acc[ 3].x); acc[ 3].y = fmaf(p0.w, kv.y, acc[ 3].y);
            acc[ 3].z = fmaf(p0.w, kv.z, acc[ 3].z); acc[ 3].w = fmaf(p0.w, kv.w, acc[ 3].w);
            acc[ 4].x = fmaf(p1.x, kv.x, acc[ 4].x); acc[ 4].y = fmaf(p1.x, kv.y, acc[ 4].y);
            acc[ 4].z = fmaf(p1.x, kv.z, acc[ 4].z); acc[ 4].w = fmaf(p1.x, kv.w, acc[ 4].w);
            acc[ 5].x = fmaf(p1.y, kv.x, acc[ 5].x); acc[ 5].y = fmaf(p1.y, kv.y, acc[ 5].y);
            acc[ 5].z = fmaf(p1.y, kv.z, acc[ 5].z); acc[ 5].w = fmaf(p1.y, kv.w, acc[ 5].w);
            acc[ 6].x = fmaf(p1.z, kv.x, acc[ 6].x); acc[ 6].y = fmaf(p1.z, kv.y, acc[ 6].y);
            acc[ 6].z = fmaf(p1.z, kv.z, acc[ 6].z); acc[ 6].w = fmaf(p1.z, kv.w, acc[ 6].w);
            acc[ 7].x = fmaf(p1.w, kv.x, acc[ 7].x); acc[ 7].y = fmaf(p1.w, kv.y, acc[ 7].y);
            acc[ 7].z = fmaf(p1.w, kv.z, acc[ 7].z); acc[ 7].w = fmaf(p1.w, kv.w, acc[ 7].w);
            acc[ 8].x = fmaf(p2.x, kv.x, acc[ 8].x); acc[ 8].y = fmaf(p2.x, kv.y, acc[ 8].y);
            acc[ 8].z = fmaf(p2.x, kv.z, acc[ 8].z); acc[ 8].w = fmaf(p2.x, kv.w, acc[ 8].w);
            acc[ 9].x = fmaf(p2.y, kv.x, acc[ 9].x); acc[ 9].y = fmaf(p2.y, kv.y, acc[ 9].y);
            acc[ 9].z = fmaf(p2.y, kv.z, acc[ 9].z); acc[ 9].w = fmaf(p2.y, kv.w, acc[ 9].w);
            acc[10].x = fmaf(p2.z, kv.x, acc[10].x); acc[10].y = fmaf(p2.z, kv.y, acc[10].y);
            acc[10].z = fmaf(p2.z, kv.z, acc[10].z); acc[10].w = fmaf(p2.z, kv.w, acc[10].w);
            acc[11].x = fmaf(p2.w, kv.x, acc[11].x); acc[11].y = fmaf(p2.w, kv.y, acc[11].y);
            acc[11].z = fmaf(p2.w, kv.z, acc[11].z); acc[11].w = fmaf(p2.w, kv.w, acc[11].w);
            acc[12].x = fmaf(p3.x, kv.x, acc[12].x); acc[12].y = fmaf(p3.x, kv.y, acc[12].y);
            acc[12].z = fmaf(p3.x, kv.z, acc[12].z); acc[12].w = fmaf(p3.x, kv.w, acc[12].w);
            acc[13].x = fmaf(p3.y, kv.x, acc[13].x); acc[13].y = fmaf(p3.y, kv.y, acc[13].y);
            acc[13].z = fmaf(p3.y, kv.z, acc[13].z); acc[13].w = fmaf(p3.y, kv.w, acc[13].w);
            acc[14].x = fmaf(p3.z, kv.x, acc[14].x); acc[14].y = fmaf(p3.z, kv.y, acc[14].y);
            acc[14].z = fmaf(p3.z, kv.z, acc[14].z); acc[14].w = fmaf(p3.z, kv.w, acc[14].w);
            acc[15].x = fmaf(p3.w, kv.x, acc[15].x); acc[15].y = fmaf(p3.w, kv.y, acc[15].y);
            acc[15].z = fmaf(p3.w, kv.z, acc[15].z); acc[15].w = fmaf(p3.w, kv.w, acc[15].w);
        }
        __syncthreads();
        pv = pnext;
    }

    // butterfly reduce over ug (lane bits 0-2); lane ug keeps slots ug, ug+8
    float4 r0 = make_float4(0.f, 0.f, 0.f, 0.f);
    float4 r1 = make_float4(0.f, 0.f, 0.f, 0.f);
    #pragma unroll
    for (int j = 0; j < TROWS; ++j) {
        float4 a = acc[j];
        #pragma unroll
        for (int m = 1; m <= 4; m <<= 1) {
            a.x += __shfl_xor(a.x, m);
            a.y += __shfl_xor(a.y, m);
            a.z += __shfl_xor(a.z, m);
            a.w += __shfl_xor(a.w, m);
        }
        if ((j & 7) == ug) { if (j < 8) r0 = a; else r1 = a; }
    }

    const int slot0 = tile * TROWS + ug;
    const int slot1 = slot0 + 8;
    if (slot0 < count) {
        const float sc = s_sc[ug];
        float* o = out + (size_t)s_o[ug] * ND + (l << 2);
        atomicAdd(o + 0, r0.x * sc);
        atomicAdd(o + 1, r0.y * sc);
        atomicAdd(o + 2, r0.z * sc);
        atomicAdd(o + 3, r0.w * sc);
    }
    if (slot1 < count) {
        const float sc = s_sc[ug + 8];
        float* o = out + (size_t)s_o[ug + 8] * ND + (l << 2);
        atomicAdd(o + 0, r1.x * sc);
        atomicAdd(o + 1, r1.y * sc);
        atomicAdd(o + 2, r1.z * sc);
        atomicAdd(o + 3, r1.w * sc);
    }
}

extern "C" void kernel_launch(void* const* d_in, const int* in_sizes, int n_in,
                              void* d_out, int out_size, void* d_ws, size_t ws_size,
                              hipStream_t stream) {
    const int*   concepts        = (const int*)d_in[0];
    const int*   concepts_length = (const int*)d_in[1];
    const int*   seg_len         = (const int*)d_in[2];
    const float* embed_w         = (const float*)d_in[3];
    const float* embed_kb_w      = (const float*)d_in[4];
    const float* edge_matrix     = (const float*)d_in[5];
    const float* affectiveness   = (const float*)d_in[6];
    const float* lam             = (const float*)d_in[7];
    float* out = (float*)d_out;

    float* wsf = (float*)d_ws;
    int*   wsi = (int*)d_ws;
    int*   counter  = wsi + WS_CNT;
    int*   meta_out = wsi + WS_METAO;
    float* f_scale  = wsf + WS_SCALE;
    float* cn       = wsf + WS_CN;
    float* cos_bv   = wsf + WS_COS;
    float* mean_j   = wsf + WS_MEANJ;
    float* pbuf     = wsf + WS_P;

    k_mean<<<NB * NS, ND, 0, stream>>>(concepts, concepts_length, embed_w,
                                       mean_j, out, counter);
    k_ctx2<<<NB, ND, 0, stream>>>(seg_len, mean_j, cn);
    k_cos<<<NV / 8, 256, 0, stream>>>(embed_kb_w, cn, cos_bv);
    k_A<<<MAXSLOTS, 256, 0, stream>>>(concepts, concepts_length, seg_len,
                                      edge_matrix, affectiveness, lam, cos_bv,
                                      counter, meta_out, f_scale, pbuf);
    dim3 gB(MAXSLOTS / TROWS, USPLIT, 1);
    k_B<<<gB, 256, 0, stream>>>(embed_kb_w, counter, meta_out, f_scale, pbuf, out);
}